// Round 8
// baseline (275.488 us; speedup 1.0000x reference)
//
#include <hip/hip_runtime.h>

// DiagLRConv: out[n,o,h,w] = sum_{k,i} fw[o,i,k] * x[n,i,h+k-2,w+k-2]
// x: (16,16,512,512) fp32, fw: (16,16,5) fp32, out fp32.
//
// Structure (R8): fp32 staged to LDS via __builtin_amdgcn_global_load_lds
// (zero VGPR involvement -> compiler cannot re-serialize staging, the R4/R6/R7
// failure mode). Borders handled by clamped staging addresses + exact fixup
// kernel. Bank conflicts killed by a source-permutation XOR (LDS linear, as
// required by gload_lds; the channel-quad is XOR-swizzled in the global source
// address and the same XOR applied on ds_read).

#define HH    512
#define WW    512
#define CH    16
#define KK    5
#define IMG   (HH * WW)
#define CHIMG (CH * IMG)

#define HT 16            // output rows per block
#define WT 32            // output px per block
#define RI 20            // staged rows (HT + 4 halo)
#define WI 36            // staged px   (WT + 4 halo)
// LDS layout: addr4(SI2, p) = SI2*8 + p ; SI2 = (ri*2 + half)*36 + wi ;
// stored p holds global channel j = p ^ F(SI2), F = ((SI2>>2)&1)<<2.
#define NSI2  (RI * 2 * WI)          // 1440 sites
#define NF32  (NSI2 * 8)             // 11520 floats = 46080 B
#define NLD   (NF32 / 64)            // 180 gload_lds(width4) per block

typedef __attribute__((ext_vector_type(8))) short bf16x8;
typedef __attribute__((ext_vector_type(4))) float f32x4;
typedef __attribute__((ext_vector_type(4))) int   i32x4;

union I4S8 { i32x4 i; bf16x8 s; };

__device__ __forceinline__ unsigned cvt_pk_bf16(float lo, float hi) {
    unsigned r;
    asm("v_cvt_pk_bf16_f32 %0, %1, %2" : "=v"(r) : "v"(lo), "v"(hi));
    return r;
}

__device__ __forceinline__ void gload_lds4(const float* g, float* l) {
    __builtin_amdgcn_global_load_lds(
        (const __attribute__((address_space(1))) void*)g,
        (__attribute__((address_space(3))) void*)l, 4, 0, 0);
}

// NOTE (R2): never cap VGPRs via __launch_bounds__ min-waves — acc spills.
__global__ __launch_bounds__(256)
void diag_conv_mfma(const float* __restrict__ x,
                    const float* __restrict__ fw,
                    float* __restrict__ out)
{
    __shared__ float xl[NF32];   // 46080 B -> 3 blocks/CU

    const int tid  = threadIdx.x;
    const int wv   = tid >> 6;
    const int lane = tid & 63;

    // Bijective XCD swizzle: 8192 blocks = 8 XCDs x 1024 contiguous (2 images).
    const int bid = blockIdx.x;
    const int swz = ((bid & 7) << 10) | (bid >> 3);
    const int n  = swz >> 9;          // 0..15
    const int ht = (swz >> 4) & 31;   // 0..31
    const int wt = swz & 15;          // 0..15
    const int h0 = ht * HT;
    const int w0 = wt * WT;

    const float* __restrict__ xn = x + (size_t)n * CHIMG;

    // ---------------- stage x -> LDS via global_load_lds (width 4) ----------
    // 180 instrs round-robin over waves; LDS dest linear (base + lane*4).
    // Global source carries the clamp (borders fixed up later) and the XOR
    // channel swizzle.
    const int l3 = lane >> 3;    // site sub-index within instr
    const int p  = lane & 7;     // stored channel slot
#pragma unroll
    for (int uu = 0; uu < NLD / 4; ++uu) {
        const int u   = uu * 4 + wv;          // wave-uniform instr id
        const int SI2 = u * 8 + l3;
        const int F   = ((SI2 >> 2) & 1) << 2;
        const int j   = p ^ F;
        const int wi  = SI2 % WI;
        const int t   = SI2 / WI;
        const int half = t & 1;
        const int ri   = t >> 1;
        const int ch   = half * 8 + j;
        int r = h0 - 2 + ri;
        r = r < 0 ? 0 : (r > HH - 1 ? HH - 1 : r);
        int w = w0 - 2 + wi;
        w = w < 0 ? 0 : (w > WW - 1 ? WW - 1 : w);
        const float* gp = xn + (((size_t)ch) << 18) + ((size_t)(r << 9) + w);
        gload_lds4(gp, xl + u * 64);
    }

    // ---------------- W fragments (B operand; verified R5/R6) ---------------
    // lane: n=o=lane&15 ; K-slot=(lane>>4)*8+j -> tap=2s+(lane>>5),
    // i=((lane>>4)&1)*8+j ; tap==5 (s=2, upper half) -> zero.
    const int px  = lane & 15;
    const int ihl = (lane >> 4) & 1;
    const int tb  = lane >> 5;

    bf16x8 wfrag[3];
#pragma unroll
    for (int s = 0; s < 3; ++s) {
        const int tap = 2 * s + tb;
        I4S8 a;
        a.i = (i32x4){0, 0, 0, 0};
        if (tap < KK) {
            const float* __restrict__ wp = fw + ((size_t)px * CH + ihl * 8) * KK + tap;
            a.i.x = (int)cvt_pk_bf16(wp[0 * KK], wp[1 * KK]);
            a.i.y = (int)cvt_pk_bf16(wp[2 * KK], wp[3 * KK]);
            a.i.z = (int)cvt_pk_bf16(wp[4 * KK], wp[5 * KK]);
            a.i.w = (int)cvt_pk_bf16(wp[6 * KK], wp[7 * KK]);
        }
        wfrag[s] = a.s;
    }

    __syncthreads();   // drains gload_lds vmcnt

    // ---------------- MFMA: per wave 4 h-rows x 2 px-groups x 3 slices ------
    float* __restrict__ outn = out + (size_t)n * CHIMG;
    const int pq = (lane >> 4) << 2;

#pragma unroll
    for (int rr = 0; rr < 4; ++rr) {
        const int r = wv * 4 + rr;
#pragma unroll
        for (int g = 0; g < 2; ++g) {
            f32x4 acc = (f32x4){0.f, 0.f, 0.f, 0.f};
#pragma unroll
            for (int s = 0; s < 3; ++s) {
                const int tap = 2 * s + tb;
                int ri = r + tap;
                ri = ri > RI - 1 ? RI - 1 : ri;       // tap-5 pad lanes only
                int wi = g * 16 + px + tap;
                wi = wi > WI - 1 ? WI - 1 : wi;       // tap-5 pad lanes only
                const int SI2 = (ri * 2 + ihl) * WI + wi;
                const int A   = SI2 * 8;
                const int F   = ((SI2 >> 2) & 1) << 2;
                const f32x4 lo = *(const f32x4*)(xl + A + F);        // ch j=0..3
                const f32x4 hi = *(const f32x4*)(xl + A + (F ^ 4));  // ch j=4..7
                I4S8 b;
                b.i.x = (int)cvt_pk_bf16(lo.x, lo.y);
                b.i.y = (int)cvt_pk_bf16(lo.z, lo.w);
                b.i.z = (int)cvt_pk_bf16(hi.x, hi.y);
                b.i.w = (int)cvt_pk_bf16(hi.z, hi.w);
                acc = __builtin_amdgcn_mfma_f32_16x16x32_bf16(
                    b.s, wfrag[s], acc, 0, 0, 0);     // A=X', B=W'
            }
            // D: col = lane&15 = o ; row = (lane>>4)*4+reg = px (verified R6)
            float* __restrict__ dst =
                outn + (size_t)px * IMG + (size_t)(h0 + r) * WW + (w0 + g * 16 + pq);
            *(f32x4*)dst = acc;
        }
    }
}

// ---------------- fixup: recompute outputs with h or w in {0,1,510,511} -----
__global__ __launch_bounds__(256)
void diag_conv_fixup(const float* __restrict__ x,
                     const float* __restrict__ fw,
                     float* __restrict__ out)
{
    __shared__ __align__(16) float Wl[KK][CH][CH];   // [k][i][o]
    const int tid = threadIdx.x;
    for (int idx = tid; idx < KK * CH * CH; idx += 256) {
        int k   = idx >> 8;
        int rem = idx & 255;
        int i   = rem >> 4;
        int o   = rem & 15;
        Wl[k][i][o] = fw[(o * CH + i) * KK + k];
    }
    __syncthreads();

    const int n = blockIdx.y;
    const int s = blockIdx.x * 256 + tid;
    if (s >= 4080) return;

    int h, w;
    if (s < 2048) {                        // h-border rows, all w
        const int c = s >> 9;
        h = c < 2 ? c : 508 + c;           // 0,1,510,511
        w = s & 511;
    } else {                               // w-border cols, h in [2,509]
        const int s2 = s - 2048;
        const int c  = s2 / 508;
        w = c < 2 ? c : 508 + c;
        h = 2 + s2 % 508;
    }

    f32x4 acc4[4];
#pragma unroll
    for (int u = 0; u < 4; ++u) acc4[u] = (f32x4){0.f, 0.f, 0.f, 0.f};

#pragma unroll
    for (int k = 0; k < KK; ++k) {
        const int hh = h + k - 2;
        const int ww = w + k - 2;
        if ((unsigned)hh >= (unsigned)HH || (unsigned)ww >= (unsigned)WW) continue;
        const float* __restrict__ xp = x + (size_t)n * CHIMG + (size_t)hh * WW + ww;
#pragma unroll
        for (int i = 0; i < CH; ++i) {
            const float xi = xp[(size_t)i * IMG];
#pragma unroll
            for (int u = 0; u < 4; ++u) {
                const f32x4 w4 = *(const f32x4*)&Wl[k][i][4 * u];
                acc4[u].x = fmaf(w4.x, xi, acc4[u].x);
                acc4[u].y = fmaf(w4.y, xi, acc4[u].y);
                acc4[u].z = fmaf(w4.z, xi, acc4[u].z);
                acc4[u].w = fmaf(w4.w, xi, acc4[u].w);
            }
        }
    }

#pragma unroll
    for (int u = 0; u < 4; ++u) {
        out[(size_t)(n * CH + 4 * u + 0) * IMG + (size_t)h * WW + w] = acc4[u].x;
        out[(size_t)(n * CH + 4 * u + 1) * IMG + (size_t)h * WW + w] = acc4[u].y;
        out[(size_t)(n * CH + 4 * u + 2) * IMG + (size_t)h * WW + w] = acc4[u].z;
        out[(size_t)(n * CH + 4 * u + 3) * IMG + (size_t)h * WW + w] = acc4[u].w;
    }
}

extern "C" void kernel_launch(void* const* d_in, const int* in_sizes, int n_in,
                              void* d_out, int out_size, void* d_ws, size_t ws_size,
                              hipStream_t stream)
{
    const float* x  = (const float*)d_in[0];
    const float* fw = (const float*)d_in[1];
    float* out      = (float*)d_out;

    // 8192 blocks = 16 n x 32 ht x 16 wt
    diag_conv_mfma<<<dim3(8192), dim3(256), 0, stream>>>(x, fw, out);
    diag_conv_fixup<<<dim3(16, 16), dim3(256), 0, stream>>>(x, fw, out);
}